// Round 4
// baseline (177.161 us; speedup 1.0000x reference)
//
#include <hip/hip_runtime.h>
#include <math.h>

// Problem constants (from reference):
//   B=8, R=50 (rafs has 2R=100 channels), C=150, H=W=128, N=4096, K=192
#define KPTS   192
#define RDIM   50
#define BDIM   8
#define HDIM   128
#define WDIM   128
#define NREL   4096
#define CDIM   150
#define LOSS_W 0.1f
#define WPB    4                           // waves (relations) per block
#define BLK    (WPB * 64)
#define PLANE  (HDIM * WDIM)
#define NBLOCKS (NREL / WPB)               // 1024 gather blocks
#define RAF_F4  (BDIM * 2 * RDIM * PLANE / 4)   // 3,276,800 float4 = 52.4 MB

// Warm kernel: stream all of rafs through the memory-side Infinity Cache in a
// SEPARATE dispatch that completes BEFORE the gather kernel starts (the
// ordering the round-2 fused attempt lacked). Pure coalesced float4 reads at
// streaming BW (~9 us); the gather kernel's scattered 64B misses then resolve
// in L3 (~400cy) instead of HBM (~900cy). Under the per-CU miss-slot bound
// (time ~ lines x latency / slots), halving latency halves the gather time.
__global__ __launch_bounds__(256) void warm_rafs_kernel(
    const float* __restrict__ rafs)
{
    const float4* __restrict__ src = (const float4*)rafs;
    float kx = 0.f, ky = 0.f, kz = 0.f, kw = 0.f;
    const int stride = gridDim.x * 256;
    for (int i = blockIdx.x * 256 + threadIdx.x; i < RAF_F4; i += stride) {
        const float4 v = src[i];
        kx += v.x; ky += v.y; kz += v.z; kw += v.w;
    }
    // Keep-alive (rule #17): prevents DCE of the loads. No store -> no write BW.
    asm volatile("" :: "v"(kx), "v"(ky), "v"(kz), "v"(kw));
}

// Gather kernel: INSTRUCTION-IDENTICAL per-relation math to the verified
// round-1 kernel (absmax=0): branchless clamp-gather, shfl-up dup check,
// wave64 shuffle reduction. Finish = round-3's verified fence+ticket
// last-block reduction (same deterministic order as the old reduce_kernel).
__global__ __launch_bounds__(BLK) void relation_partial_kernel(
    const float* __restrict__ rafs,      // (B, 2R, H, W)
    const float* __restrict__ heatmaps,  // (B, C, H, W)
    const int*   __restrict__ rels,      // (N, 8)
    float* __restrict__ ws,              // [0,NREL): partials; [NREL]: int ticket (pre-zeroed)
    float* __restrict__ out)             // scalar loss
{
    const int tid  = threadIdx.x;
    const int wave = tid >> 6;
    const int lane = tid & 63;
    const int rel  = blockIdx.x * WPB + wave;

    // Two 16B loads instead of eight 4B loads; then broadcast to SGPRs.
    const int4* r4 = (const int4*)(rels + (size_t)rel * 8);
    const int4 ra = r4[0];   // bi, scls, sy, sx
    const int4 rb = r4[1];   // ocls, oy, ox, pred
    const int bi   = __builtin_amdgcn_readfirstlane(ra.x);
    const int scls = __builtin_amdgcn_readfirstlane(ra.y);
    const int sy   = __builtin_amdgcn_readfirstlane(ra.z);
    const int sx   = __builtin_amdgcn_readfirstlane(ra.w);
    const int ocls = __builtin_amdgcn_readfirstlane(rb.x);
    const int oy   = __builtin_amdgcn_readfirstlane(rb.y);
    const int ox   = __builtin_amdgcn_readfirstlane(rb.z);
    const int pred = __builtin_amdgcn_readfirstlane(rb.w);

    // Scalar-address loads; latency overlaps the whole sample pipeline.
    const float subj = heatmaps[(((size_t)bi * CDIM + (size_t)scls) * HDIM + (size_t)sy) * WDIM + (size_t)sx];
    const float obj  = heatmaps[(((size_t)bi * CDIM + (size_t)ocls) * HDIM + (size_t)oy) * WDIM + (size_t)ox];

    const float dx = (float)(ox - sx);
    const float dy = (float)(oy - sy);
    const float norms = sqrtf(dx * dx + dy * dy);
    const float ux = dx / norms;
    const float uy = dy / norms;
    const int   num = (int)ceilf(norms);           // 1..180 < 192
    const float denom = (float)((num - 1) > 1 ? (num - 1) : 1);

    const float oxf = (float)ox, oyf = (float)oy;
    const float sxmox = (float)(sx - ox);
    const float symoy = (float)(sy - oy);

    const size_t rafbase =
        ((size_t)bi * (2 * RDIM) + (size_t)(2 * pred)) * (size_t)PLANE;

    // ---- Phase 1: all sample points, all gathers issued branchlessly.
    int   pxs[3], pys[3];
    float vxs[3], vys[3];
    #pragma unroll
    for (int s = 0; s < 3; ++s) {
        const int k  = lane + 64 * s;
        const int kk = (k < num) ? k : (num - 1);       // clamp: safe addr, same line
        const float t  = (float)kk / denom;             // EXACT reference expression
        const int   px = (int)rintf(oxf + t * sxmox);
        const int   py = (int)rintf(oyf + t * symoy);
        pxs[s] = px;
        pys[s] = py;
        const size_t off = (size_t)py * WDIM + (size_t)px;
        vxs[s] = rafs[rafbase + off];
        vys[s] = rafs[rafbase + (size_t)PLANE + off];
    }

    // ---- Phase 2: masked accumulate; neighbor lane supplies the bitwise-
    // exact previous px/py for the dup check.
    float dot  = 0.0f;
    int   vcnt = 0;
    int   px63 = -1, py63 = -1;
    #pragma unroll
    for (int s = 0; s < 3; ++s) {
        int pxp = __shfl_up(pxs[s], 1, 64);
        int pyp = __shfl_up(pys[s], 1, 64);
        if (lane == 0) { pxp = px63; pyp = py63; }
        px63 = __shfl(pxs[s], 63, 64);
        py63 = __shfl(pys[s], 63, 64);

        const int  k   = lane + 64 * s;
        const bool dup = (pxs[s] == pxp) && (pys[s] == pyp);
        if ((k < num) && !dup) {
            float vx = fminf(fmaxf(vxs[s], -1.0f), 1.0f);
            float vy = fminf(fmaxf(vys[s], -1.0f), 1.0f);
            dot  += vx * ux + vy * uy;
            vcnt += 1;
        }
    }

    // Wave64 shuffle reduction.
    #pragma unroll
    for (int off = 32; off > 0; off >>= 1) {
        dot  += __shfl_down(dot,  off, 64);
        vcnt += __shfl_down(vcnt, off, 64);
    }

    if (lane == 0) {
        float integral = dot / (float)vcnt;          // vcnt >= 1 (k=0 always valid)
        integral = fminf(fmaxf(integral, 0.0f), 1.0f);
        const float rs = subj * obj * integral;
        ws[rel] = logf(fmaxf(rs, 1e-12f));
    }

    // ---- Finish: last arriving block does the (order-fixed, deterministic)
    // final reduction. Verified bit-exact in round 3.
    __shared__ int amLast;
    __syncthreads();
    if (tid == 0) {
        __threadfence();                              // release: flush this XCD's L2
        int* cnt = (int*)(ws + NREL);                 // pre-zeroed via hipMemsetAsync
        const int old = atomicAdd(cnt, 1);            // device-scope
        amLast = (old == NBLOCKS - 1) ? 1 : 0;
        if (amLast) __threadfence();                  // acquire: invalidate before reads
    }
    __syncthreads();

    if (amLast) {
        float acc = 0.0f;
        #pragma unroll
        for (int j = 0; j < NREL / BLK; ++j)          // identical order to old reduce_kernel
            acc += ws[tid + j * BLK];

        #pragma unroll
        for (int off = 32; off > 0; off >>= 1)
            acc += __shfl_down(acc, off, 64);

        __shared__ float s[WPB];
        if (lane == 0) s[wave] = acc;
        __syncthreads();
        if (tid == 0) {
            const float total = s[0] + s[1] + s[2] + s[3];
            out[0] = total * (-LOSS_W / (float)NREL);
        }
    }
}

extern "C" void kernel_launch(void* const* d_in, const int* in_sizes, int n_in,
                              void* d_out, int out_size, void* d_ws, size_t ws_size,
                              hipStream_t stream) {
    const float* rafs     = (const float*)d_in[0];
    const float* heatmaps = (const float*)d_in[1];
    const int*   rels     = (const int*)d_in[2];
    float*       out      = (float*)d_out;
    float*       part     = (float*)d_ws;

    // Zero the 4-byte ticket counter (workspace is poisoned before every
    // iteration). hipMemsetAsync is graph-capturable.
    hipMemsetAsync((void*)(part + NREL), 0, sizeof(int), stream);

    // 1) Warm L3 with rafs (ordered BEFORE the gather kernel by the stream).
    warm_rafs_kernel<<<2048, 256, 0, stream>>>(rafs);

    // 2) Scattered gather + per-relation logp + fused deterministic reduce.
    relation_partial_kernel<<<NBLOCKS, BLK, 0, stream>>>(rafs, heatmaps, rels, part, out);
}

// Round 5
// 137.927 us; speedup vs baseline: 1.2845x; 1.2845x over previous
//
#include <hip/hip_runtime.h>
#include <math.h>

// Problem constants (from reference):
//   B=8, R=50 (rafs has 2R=100 channels), C=150, H=W=128, N=4096, K=192
#define KPTS   192
#define RDIM   50
#define HDIM   128
#define WDIM   128
#define NREL   4096
#define CDIM   150
#define LOSS_W 0.1f
#define WPB    4          // waves (relations) per block
#define BLK    (WPB * 64)

// ============================================================================
// REVERT to the round-0 kernel (verified: 137.5 us, absmax = 0).
//
// Session evidence for why this structure is near the floor:
//  - R1 branchless 6-deep gather MLP: neutral (138.7)  -> not latency-chain-bound
//  - R2 LDS plane staging (1 blk/CU):  161.3 regress  -> occupancy-killed
//  - R2 fused L3 warm:                 174.8 regress  -> no intra-dispatch order
//  - R3 separate L3 warm + ticket:     177.2 regress  -> warm costs > it saves;
//       per-block device-scope release fences (~1024x) add ~15-20 us
// Model: gather is per-CU miss-queue bound on poison-cooled caches
//   (~2.1K lines/CU x ~900 cy / ~32-64 outstanding ~= 20-25 us); the
//   remaining ~110 us is harness poison fills (2 x 47 us @ 84% HBM peak)
//   + launch gaps + the 1-block reduce.
// ============================================================================

// Stage 1: one wave per relation. Lane l covers samples k = l, l+64, l+128.
// All wave-uniform fields forced scalar via readfirstlane so address math is
// SALU and loads use SGPR bases. Writes per-relation logp to ws[rel]. No atomics.
__global__ __launch_bounds__(BLK) void relation_partial_kernel(
    const float* __restrict__ rafs,      // (B, 2R, H, W)
    const float* __restrict__ heatmaps,  // (B, C, H, W)
    const int*   __restrict__ rels,      // (N, 8)
    float* __restrict__ ws)              // (N,) per-relation logp
{
    const int wave = threadIdx.x >> 6;
    const int lane = threadIdx.x & 63;
    const int rel  = blockIdx.x * WPB + wave;

    // Two 16B loads instead of eight 4B loads; then broadcast to SGPRs.
    const int4* r4 = (const int4*)(rels + (size_t)rel * 8);
    const int4 ra = r4[0];   // bi, scls, sy, sx
    const int4 rb = r4[1];   // ocls, oy, ox, pred
    const int bi   = __builtin_amdgcn_readfirstlane(ra.x);
    const int scls = __builtin_amdgcn_readfirstlane(ra.y);
    const int sy   = __builtin_amdgcn_readfirstlane(ra.z);
    const int sx   = __builtin_amdgcn_readfirstlane(ra.w);
    const int ocls = __builtin_amdgcn_readfirstlane(rb.x);
    const int oy   = __builtin_amdgcn_readfirstlane(rb.y);
    const int ox   = __builtin_amdgcn_readfirstlane(rb.z);
    const int pred = __builtin_amdgcn_readfirstlane(rb.w);

    // Issue subj/obj loads early (scalar addresses -> s_load path); latency
    // overlaps the whole sample loop. Only lane 0 consumes the values.
    const float subj = heatmaps[(((size_t)bi * CDIM + (size_t)scls) * HDIM + (size_t)sy) * WDIM + (size_t)sx];
    const float obj  = heatmaps[(((size_t)bi * CDIM + (size_t)ocls) * HDIM + (size_t)oy) * WDIM + (size_t)ox];

    const float dx = (float)(ox - sx);
    const float dy = (float)(oy - sy);
    const float norms = sqrtf(dx * dx + dy * dy);
    const float ux = dx / norms;
    const float uy = dy / norms;
    const int   num = (int)ceilf(norms);           // 1..180 < 192
    const float denom = (float)((num - 1) > 1 ? (num - 1) : 1);

    const float oxf = (float)ox, oyf = (float)oy;
    const float sxmox = (float)(sx - ox);
    const float symoy = (float)(sy - oy);

    const size_t rafbase =
        ((size_t)bi * (2 * RDIM) + (size_t)(2 * pred)) * (HDIM * WDIM);

    float dot  = 0.0f;
    int   vcnt = 0;

    #pragma unroll
    for (int s = 0; s < 3; ++s) {
        const int k = lane + 64 * s;
        if (k < num) {                               // exec-mask skip when no lane active
            const float t  = (float)k / denom;
            const int   px = (int)rintf(oxf + t * sxmox);
            const int   py = (int)rintf(oyf + t * symoy);
            bool dup = false;
            if (k > 0) {
                const float tp  = (float)(k - 1) / denom;
                const int   pxp = (int)rintf(oxf + tp * sxmox);
                const int   pyp = (int)rintf(oyf + tp * symoy);
                dup = (px == pxp) && (py == pyp);
            }
            if (!dup) {
                const size_t off = (size_t)py * WDIM + (size_t)px;
                float vx = rafs[rafbase + off];
                float vy = rafs[rafbase + (size_t)(HDIM * WDIM) + off];
                vx = fminf(fmaxf(vx, -1.0f), 1.0f);
                vy = fminf(fmaxf(vy, -1.0f), 1.0f);
                dot  += vx * ux + vy * uy;
                vcnt += 1;
            }
        }
    }

    // Wave64 shuffle reduction.
    #pragma unroll
    for (int off = 32; off > 0; off >>= 1) {
        dot  += __shfl_down(dot,  off, 64);
        vcnt += __shfl_down(vcnt, off, 64);
    }

    if (lane == 0) {
        float integral = dot / (float)vcnt;          // vcnt >= 1 (k=0 always valid)
        integral = fminf(fmaxf(integral, 0.0f), 1.0f);
        const float rs = subj * obj * integral;
        ws[rel] = logf(fmaxf(rs, 1e-12f));
    }
}

// Stage 2: deterministic sum of NREL partials -> scalar loss. One block.
__global__ __launch_bounds__(256) void reduce_kernel(
    const float* __restrict__ part,   // (NREL,)
    float* __restrict__ out)
{
    const int tid = threadIdx.x;
    float acc = 0.0f;
    #pragma unroll
    for (int j = 0; j < NREL / 256; ++j)
        acc += part[tid + j * 256];

    #pragma unroll
    for (int off = 32; off > 0; off >>= 1)
        acc += __shfl_down(acc, off, 64);

    __shared__ float s[4];
    const int wave = tid >> 6;
    const int lane = tid & 63;
    if (lane == 0) s[wave] = acc;
    __syncthreads();
    if (tid == 0) {
        const float total = s[0] + s[1] + s[2] + s[3];
        out[0] = total * (-LOSS_W / (float)NREL);
    }
}

extern "C" void kernel_launch(void* const* d_in, const int* in_sizes, int n_in,
                              void* d_out, int out_size, void* d_ws, size_t ws_size,
                              hipStream_t stream) {
    const float* rafs     = (const float*)d_in[0];
    const float* heatmaps = (const float*)d_in[1];
    const int*   rels     = (const int*)d_in[2];
    float*       out      = (float*)d_out;
    float*       part     = (float*)d_ws;

    relation_partial_kernel<<<NREL / WPB, BLK, 0, stream>>>(rafs, heatmaps, rels, part);
    reduce_kernel<<<1, 256, 0, stream>>>(part, out);
}